// Round 2
// baseline (250.739 us; speedup 1.0000x reference)
//
#include <hip/hip_runtime.h>
#include <hip/hip_bf16.h>
#include <cmath>

#define H 8
#define D 128
#define HD 1024            // H*D
#define NMAX 1024
#define BS 32
#define NB 32
#define S_SEL 8
#define CHUNK 8            // kb blocks per slc_attn workgroup
#define MC 4               // max chunks per mtile (ceil(32/CHUNK))
#define SCALE 0.08838834764831845f   // 1/sqrt(128)
#define SENT -3.0e38f

typedef __attribute__((ext_vector_type(8))) short short8;   // 8 bf16 = 4 VGPRs
typedef __attribute__((ext_vector_type(4))) float f32x4;    // MFMA acc

#define MFMA16(a, b, c) __builtin_amdgcn_mfma_f32_16x16x32_bf16(a, b, c, 0, 0, 0)

__device__ __forceinline__ float silu(float x) {
    return x / (1.f + expf(-x));
}
__device__ __forceinline__ unsigned short f2bf(float x) {
    return __builtin_bit_cast(unsigned short, __float2bfloat16(x));
}
__device__ __forceinline__ float bfup(unsigned short b) {
    unsigned u = (unsigned)b << 16;
    return __builtin_bit_cast(float, u);
}
// 3-term bf16 split: x ~= b0 + b1 + b2 with |err| ~ 2^-27 |x|
__device__ __forceinline__ void split3(float x, unsigned short& b0,
                                       unsigned short& b1, unsigned short& b2) {
    b0 = f2bf(x);
    float r1 = x - bfup(b0);
    b1 = f2bf(r1);
    float r2 = r1 - bfup(b1);
    b2 = f2bf(r2);
}

// ---------------------------------------------------------------------------
// K1 prep: per (b,h,nt) 32-token block:
//   - kb16[tok][h][d]   : bf16 copy of K (straight convert, coalesced)
//   - vt_blk[bh][nt][d][j]: bf16 V^T in 8KB contiguous blocks (LDS transpose)
//   - g[b,m,h,{0,1}]    : gates (8-lane reduction, lanes share (tok,h))
// ---------------------------------------------------------------------------
__global__ __launch_bounds__(256) void prep_kernel(
    const float* __restrict__ q, const float* __restrict__ k,
    const float* __restrict__ v, const float* __restrict__ Wg,
    const float* __restrict__ bg, const int* __restrict__ offs,
    unsigned short* __restrict__ kb16, unsigned short* __restrict__ vt_blk,
    float* __restrict__ g) {
    int x = blockIdx.x;
    int nt = x & (NB - 1);
    int h = (x >> 5) & 7;
    int b = x >> 8;
    int o0 = offs[b];
    int len = offs[b + 1] - o0;
    if (nt * BS >= len) return;

    __shared__ __align__(16) unsigned short tile[128 * 40];
    int tid = threadIdx.x;
    int j = tid >> 3, dc = tid & 7;
    size_t base = (size_t)(o0 + nt * BS + j) * HD + h * D + dc * 16;

    // K -> kb16 (bf16, same layout)
    {
        float xv[16];
        *(float4*)(xv + 0)  = *(const float4*)(k + base);
        *(float4*)(xv + 4)  = *(const float4*)(k + base + 4);
        *(float4*)(xv + 8)  = *(const float4*)(k + base + 8);
        *(float4*)(xv + 12) = *(const float4*)(k + base + 12);
        short8 lo, hi;
#pragma unroll
        for (int i = 0; i < 8; i++) { lo[i] = (short)f2bf(xv[i]); hi[i] = (short)f2bf(xv[8 + i]); }
        *(short8*)(kb16 + base) = lo;
        *(short8*)(kb16 + base + 8) = hi;
    }
    // V -> LDS transpose tile[d][j]
    {
        float xv[16];
        *(float4*)(xv + 0)  = *(const float4*)(v + base);
        *(float4*)(xv + 4)  = *(const float4*)(v + base + 4);
        *(float4*)(xv + 8)  = *(const float4*)(v + base + 8);
        *(float4*)(xv + 12) = *(const float4*)(v + base + 12);
#pragma unroll
        for (int i = 0; i < 16; i++) tile[(dc * 16 + i) * 40 + j] = f2bf(xv[i]);
    }
    // gates (dot over this thread's 16 dims, reduce across 8 dc-lanes)
    {
        float xv[16];
        *(float4*)(xv + 0)  = *(const float4*)(q + base);
        *(float4*)(xv + 4)  = *(const float4*)(q + base + 4);
        *(float4*)(xv + 8)  = *(const float4*)(q + base + 8);
        *(float4*)(xv + 12) = *(const float4*)(q + base + 12);
        float p0 = 0.f, p1 = 0.f;
#pragma unroll
        for (int i = 0; i < 16; i++) {
            int wb = (h * D + dc * 16 + i) * 3;
            p0 += xv[i] * Wg[wb + 0];
            p1 += xv[i] * Wg[wb + 1];
        }
#pragma unroll
        for (int off = 4; off > 0; off >>= 1) {
            p0 += __shfl_xor(p0, off);
            p1 += __shfl_xor(p1, off);
        }
        if (dc == 0) {
            float g0 = 1.f / (1.f + expf(-(p0 + bg[h * 3 + 0])));
            float g1 = 1.f / (1.f + expf(-(p1 + bg[h * 3 + 1])));
            float* gp = g + (size_t)((b * NMAX + nt * BS + j) * H + h) * 2;
            gp[0] = g0; gp[1] = g1;
        }
    }
    __syncthreads();
    // tile -> vt_blk (contiguous 8KB per (bh,nt))
    {
        int d = tid >> 1, hf = tid & 1;
        short8 a = *(const short8*)(tile + d * 40 + hf * 16);
        short8 c = *(const short8*)(tile + d * 40 + hf * 16 + 8);
        size_t ob = ((size_t)((b * H + h) * NB + nt) * 128 + d) * 32 + hf * 16;
        *(short8*)(vt_blk + ob) = a;
        *(short8*)(vt_blk + ob + 8) = c;
    }
}

// ---------------------------------------------------------------------------
// K2: block compression means (fp32 — selection precision depends on it)
// ---------------------------------------------------------------------------
__global__ __launch_bounds__(256) void compress_kernel(
    const float* __restrict__ k, const float* __restrict__ v,
    const int* __restrict__ offs,
    float* __restrict__ k_cmp, float* __restrict__ v_cmp) {
    int idx = blockIdx.x * 256 + threadIdx.x;       // float4 index over [B,NB,H,D/4]
    int d4 = idx & 31;
    int h  = (idx >> 5) & 7;
    int kb = (idx >> 8) & (NB - 1);
    int b  = idx >> 13;
    int o0 = offs[b];
    int len = offs[b + 1] - o0;
    float4 ks = make_float4(0.f, 0.f, 0.f, 0.f);
    float4 vs = ks;
    int base = kb * BS;
#pragma unroll 4
    for (int j = 0; j < BS; j++) {
        int pos = base + j;
        if (pos < len) {
            size_t src = (size_t)(o0 + pos) * HD + h * D + d4 * 4;
            float4 kk = *(const float4*)(k + src);
            float4 vv = *(const float4*)(v + src);
            ks.x += kk.x; ks.y += kk.y; ks.z += kk.z; ks.w += kk.w;
            vs.x += vv.x; vs.y += vv.y; vs.z += vv.z; vs.w += vv.w;
        }
    }
    const float inv = 1.f / 32.f;
    ks.x *= inv; ks.y *= inv; ks.z *= inv; ks.w *= inv;
    vs.x *= inv; vs.y *= inv; vs.z *= inv; vs.w *= inv;
    *(float4*)(k_cmp + (size_t)idx * 4) = ks;
    *(float4*)(v_cmp + (size_t)idx * 4) = vs;
}

// ---------------------------------------------------------------------------
// K3a: compressed attention + top-8 selection, ONE 32-row q-block per WG.
// Uniform work per block -> grid B*H*NB (~800 active), good occupancy.
// 3-plane split-bf16 MFMA QK (fp32-equivalent selection scores), silu ->
// o_cmp PV, top-8 -> ms_g (global bitmask per row).
// MFMA layouts (m89/m120): A[m=lane&15][k=quad*8+j]; C/D col=lane&15,
// row=quad*4+reg.
// ---------------------------------------------------------------------------
__global__ __launch_bounds__(256) void cmp_attn(
    const float* __restrict__ q, const float* __restrict__ k_cmp,
    const float* __restrict__ v_cmp, const float* __restrict__ g,
    const int* __restrict__ offs, unsigned* __restrict__ ms_g,
    float* __restrict__ o_cmp_j) {
    int x = blockIdx.x;                 // (b*H + h)*NB + qblk
    int qblk = x & (NB - 1);
    int h = (x >> 5) & 7;
    int b = x >> 8;
    int o0 = offs[b];
    int len = offs[b + 1] - o0;
    if (qblk * BS >= len) return;

    // pool: R0/R1/R2 k_cmp planes (32x136), R3 v_cmp^T (128x40), Ps (32x40)
    __shared__ __align__(16) unsigned short pool[19456];
    __shared__ float Ss[32 * 33];
    unsigned short* R0 = pool;           // 4352
    unsigned short* R1 = pool + 4352;    // 4352
    unsigned short* R2 = pool + 8704;    // 4352
    unsigned short* R3 = pool + 13056;   // 5120
    unsigned short* Ps = pool + 18176;   // 1280 (32x40)

    int tid = threadIdx.x;
    int w = tid >> 6, lane = tid & 63;
    int r = lane & 15, quad = lane >> 4;
    int mt = w >> 1, jt = w & 1;        // row-half / col-half quadrant
    int stg_j = tid >> 3, stg_dc = tid & 7;

    // ---- stage k_cmp 3 planes + v_cmp^T ----
    {
        const float* src = k_cmp + ((size_t)(b * NB + stg_j) * H + h) * D + stg_dc * 16;
        float xv[16];
        *(float4*)(xv + 0)  = *(const float4*)(src);
        *(float4*)(xv + 4)  = *(const float4*)(src + 4);
        *(float4*)(xv + 8)  = *(const float4*)(src + 8);
        *(float4*)(xv + 12) = *(const float4*)(src + 12);
        short8 a0, a1, a2, b0, b1, b2;
#pragma unroll
        for (int i = 0; i < 8; i++) {
            unsigned short e0, e1, e2;
            split3(xv[i], e0, e1, e2);
            a0[i] = (short)e0; a1[i] = (short)e1; a2[i] = (short)e2;
            split3(xv[8 + i], e0, e1, e2);
            b0[i] = (short)e0; b1[i] = (short)e1; b2[i] = (short)e2;
        }
        int ofs = stg_j * 136 + stg_dc * 16;
        *(short8*)(R0 + ofs) = a0; *(short8*)(R0 + ofs + 8) = b0;
        *(short8*)(R1 + ofs) = a1; *(short8*)(R1 + ofs + 8) = b1;
        *(short8*)(R2 + ofs) = a2; *(short8*)(R2 + ofs + 8) = b2;
        const float* vb = v_cmp + ((size_t)(b * NB + stg_j) * H + h) * D;
#pragma unroll
        for (int i = 0; i < 16; i++) {
            int d = stg_dc + 8 * i;
            R3[d * 40 + stg_j] = f2bf(vb[d]);
        }
    }
    __syncthreads();

    // ---- Q fragments (3 planes), QK ----
    short8 qf0[4], qf1[4], qf2[4];
    {
        const float* qrow = q + (size_t)(o0 + qblk * BS + mt * 16 + r) * HD + h * D;
#pragma unroll
        for (int s = 0; s < 4; s++) {
            const float* p0 = qrow + s * 32 + quad * 8;
            float xv[8];
            *(float4*)(xv) = *(const float4*)p0;
            *(float4*)(xv + 4) = *(const float4*)(p0 + 4);
            short8 f0, f1, f2;
#pragma unroll
            for (int i = 0; i < 8; i++) {
                unsigned short e0, e1, e2;
                split3(xv[i], e0, e1, e2);
                f0[i] = (short)e0; f1[i] = (short)e1; f2[i] = (short)e2;
            }
            qf0[s] = f0; qf1[s] = f1; qf2[s] = f2;
        }
    }
    // QK: 6 product rounds, small terms first
    f32x4 sv = (f32x4){0.f, 0.f, 0.f, 0.f};
#pragma unroll
    for (int s = 0; s < 4; s++) {
        int ofs = (jt * 16 + r) * 136 + s * 32 + quad * 8;
        short8 k0 = *(const short8*)(R0 + ofs);
        short8 k1 = *(const short8*)(R1 + ofs);
        short8 k2 = *(const short8*)(R2 + ofs);
        sv = MFMA16(qf1[s], k1, sv);
        sv = MFMA16(qf0[s], k2, sv);
        sv = MFMA16(qf2[s], k0, sv);
        sv = MFMA16(qf0[s], k1, sv);
        sv = MFMA16(qf1[s], k0, sv);
        sv = MFMA16(qf0[s], k0, sv);
    }
    int colj = jt * 16 + r;
    bool causal = (colj <= qblk);
#pragma unroll
    for (int i = 0; i < 4; i++) {
        int mrow = mt * 16 + quad * 4 + i;      // 0..31
        float sc = sv[i] * SCALE;
        Ss[mrow * 33 + colj] = causal ? sc : SENT;
        Ps[mrow * 40 + colj] = f2bf(causal ? silu(sc) : 0.f);
    }
    __syncthreads();

    // ---- PV -> o_cmp ----
    f32x4 accC[2][2];
#pragma unroll
    for (int a = 0; a < 2; a++)
#pragma unroll
        for (int c = 0; c < 2; c++) accC[a][c] = (f32x4){0.f, 0.f, 0.f, 0.f};
    {
        short8 pf0 = *(const short8*)(Ps + r * 40 + quad * 8);
        short8 pf1 = *(const short8*)(Ps + (16 + r) * 40 + quad * 8);
        short8 vf0 = *(const short8*)(R3 + ((2 * w + 0) * 16 + r) * 40 + quad * 8);
        short8 vf1 = *(const short8*)(R3 + ((2 * w + 1) * 16 + r) * 40 + quad * 8);
        accC[0][0] = MFMA16(pf0, vf0, accC[0][0]);
        accC[0][1] = MFMA16(pf0, vf1, accC[0][1]);
        accC[1][0] = MFMA16(pf1, vf0, accC[1][0]);
        accC[1][1] = MFMA16(pf1, vf1, accC[1][1]);
    }
    // ---- selection -> ms_g ----
    size_t msbase = ((size_t)(b * H + h) << 10) + (size_t)qblk * BS;
    if (qblk < S_SEL) {
        if (tid < BS) ms_g[msbase + tid] = (1u << (qblk + 1)) - 1u;
    } else {
        int h2 = lane >> 5, l32 = lane & 31;
#pragma unroll
        for (int pass = 0; pass < 4; pass++) {
            int row = w * 8 + pass * 2 + h2;
            float val = Ss[row * 33 + l32];
            unsigned mask = 0;
            bool taken = false;
            for (int it = 0; it < S_SEL; it++) {
                float vv = taken ? SENT : val;
                int idx = l32;
#pragma unroll
                for (int off = 16; off > 0; off >>= 1) {
                    float ov = __shfl_xor(vv, off);
                    int oi = __shfl_xor(idx, off);
                    if (ov > vv || (ov == vv && oi < idx)) { vv = ov; idx = oi; }
                }
                if (vv > -2.9e38f) {
                    mask |= (1u << idx);
                    if (idx == l32) taken = true;
                }
            }
            if (l32 == 0) ms_g[msbase + row] = mask;
        }
    }
    // ---- epilogue o_cmp ----
#pragma unroll
    for (int mtl = 0; mtl < 2; mtl++) {
#pragma unroll
        for (int i = 0; i < 4; i++) {
            int mrow = mtl * 16 + quad * 4 + i;
            int gm = qblk * BS + mrow;
            float gc = g[(size_t)((b * NMAX + gm) * H + h) * 2];
            float* dst = o_cmp_j + (size_t)(o0 + gm) * HD + h * D;
            dst[(2 * w + 0) * 16 + r] = accC[mtl][0][i] * gc;
            dst[(2 * w + 1) * 16 + r] = accC[mtl][1][i] * gc;
        }
    }
}

// ---------------------------------------------------------------------------
// K3b: selected attention, CHUNKED over kb. Block = (b,h,mtile,chunk):
// 64 q-rows x up to CHUNK=8 kb-blocks, double-buffered K/V staging from
// pre-converted bf16 kb16/vt_blk, per-row mask(ms_g)+causal, silu, PV,
// fp32 partial accumulate -> atomicAdd into pre-zeroed o_slc_j (plain store
// for single-chunk tiles, mtile<=3). Equal-size work items kill the
// mtile-proportional tail that capped occupancy at 12%.
// ---------------------------------------------------------------------------
__global__ __launch_bounds__(256) void slc_attn(
    const float* __restrict__ q, const unsigned short* __restrict__ kb16,
    const unsigned short* __restrict__ vt_blk, const float* __restrict__ g,
    const int* __restrict__ offs, const unsigned* __restrict__ ms_g,
    float* __restrict__ o_slc_j) {
    int x = blockIdx.x;                 // (((b*H + h)*16 + mtile)*MC + chunk)
    int chunk = x & (MC - 1);
    int mtile = (x >> 2) & 15;
    int h = (x >> 6) & 7;
    int b = x >> 9;
    int o0 = offs[b];
    int len = offs[b + 1] - o0;
    if (mtile * 64 >= len) return;      // uniform exit (lens are multiples of 64)
    int qmax = 2 * mtile + 1;
    int kb0 = chunk * CHUNK;
    if (kb0 > qmax) return;
    int kend = min(qmax, kb0 + CHUNK - 1);

    // single pool (avoids addrspacecast static-init bug with ptr arrays):
    // Kbuf0 | Kbuf1 (32x136 each) | VTbuf0 | VTbuf1 (128x40 each) | Ps (64x40)
    __shared__ __align__(16) unsigned short pool[21504];
    __shared__ unsigned Ms[64];
    unsigned short* Kst0 = pool;             // 4352
    unsigned short* Kst1 = pool + 4352;      // 4352
    unsigned short* Vst0 = pool + 8704;      // 5120
    unsigned short* Vst1 = pool + 13824;     // 5120
    unsigned short* Ps   = pool + 18944;     // 2560

    int tid = threadIdx.x;
    int w = tid >> 6, lane = tid & 63;
    int r = lane & 15, quad = lane >> 4;
    int stg_j = tid >> 3, stg_dc = tid & 7;

    if (tid < 64)
        Ms[tid] = ms_g[((size_t)(b * H + h) << 10) + mtile * 64 + tid];

    // Q fragments (plane 0): wave w -> rows 16w + r
    short8 qs[4];
    {
        const float* qrow = q + (size_t)(o0 + mtile * 64 + w * 16 + r) * HD + h * D;
#pragma unroll
        for (int s = 0; s < 4; s++) {
            const float* p0 = qrow + s * 32 + quad * 8;
            float xv[8];
            *(float4*)(xv) = *(const float4*)p0;
            *(float4*)(xv + 4) = *(const float4*)(p0 + 4);
            short8 f;
#pragma unroll
            for (int i = 0; i < 8; i++) f[i] = (short)f2bf(xv[i]);
            qs[s] = f;
        }
    }
    f32x4 acc[4][2];
#pragma unroll
    for (int a = 0; a < 4; a++)
#pragma unroll
        for (int c = 0; c < 2; c++) acc[a][c] = (f32x4){0.f, 0.f, 0.f, 0.f};

    size_t vtbase = (size_t)((b * H + h) * NB) * 4096;
    int vd = tid >> 1, vhf = tid & 1;

    // prestage kb0 into Kst0 / Vst0
    {
        const unsigned short* ks = kb16 + (size_t)(o0 + kb0 * BS + stg_j) * HD + h * D + stg_dc * 16;
        short8 k0 = *(const short8*)ks;
        short8 k1 = *(const short8*)(ks + 8);
        *(short8*)(Kst0 + stg_j * 136 + stg_dc * 16) = k0;
        *(short8*)(Kst0 + stg_j * 136 + stg_dc * 16 + 8) = k1;
        const unsigned short* vs = vt_blk + vtbase + (size_t)kb0 * 4096 + tid * 16;
        short8 v0 = *(const short8*)vs;
        short8 v1 = *(const short8*)(vs + 8);
        *(short8*)(Vst0 + vd * 40 + vhf * 16) = v0;
        *(short8*)(Vst0 + vd * 40 + vhf * 16 + 8) = v1;
    }
    __syncthreads();

    int c = 0;
    for (int kb = kb0; kb <= kend; kb++) {
        short8 pk0, pk1, pv0, pv1;
        bool pf = (kb < kend);
        if (pf) {                       // prefetch kb+1 into registers
            const unsigned short* ks = kb16 + (size_t)(o0 + (kb + 1) * BS + stg_j) * HD + h * D + stg_dc * 16;
            pk0 = *(const short8*)ks;
            pk1 = *(const short8*)(ks + 8);
            const unsigned short* vs = vt_blk + vtbase + (size_t)(kb + 1) * 4096 + tid * 16;
            pv0 = *(const short8*)vs;
            pv1 = *(const short8*)(vs + 8);
        }
        // QK: wave w -> rows [16w,16w+16), both j-frags
        unsigned short* K = c ? Kst1 : Kst0;
        f32x4 s0 = (f32x4){0.f, 0.f, 0.f, 0.f};
        f32x4 s1 = (f32x4){0.f, 0.f, 0.f, 0.f};
#pragma unroll
        for (int s = 0; s < 4; s++) {
            short8 kf0 = *(const short8*)(K + r * 136 + s * 32 + quad * 8);
            short8 kf1 = *(const short8*)(K + (16 + r) * 136 + s * 32 + quad * 8);
            s0 = MFMA16(qs[s], kf0, s0);
            s1 = MFMA16(qs[s], kf1, s1);
        }
#pragma unroll
        for (int jf = 0; jf < 2; jf++) {
            f32x4 svv = jf ? s1 : s0;
            int colj = jf * 16 + r;
            int kpos = kb * BS + colj;
#pragma unroll
            for (int i = 0; i < 4; i++) {
                int mrow = w * 16 + quad * 4 + i;
                int mpos = mtile * 64 + mrow;
                float p = (((Ms[mrow] >> kb) & 1u) && (kpos <= mpos))
                          ? silu(svv[i] * SCALE) : 0.f;
                Ps[mrow * 40 + colj] = f2bf(p);
            }
        }
        __syncthreads();
        // PV: wave w -> d-frags {2w, 2w+1}, all 4 m-frags
        unsigned short* V = c ? Vst1 : Vst0;
        {
            short8 vf0 = *(const short8*)(V + ((2 * w + 0) * 16 + r) * 40 + quad * 8);
            short8 vf1 = *(const short8*)(V + ((2 * w + 1) * 16 + r) * 40 + quad * 8);
#pragma unroll
            for (int mf = 0; mf < 4; mf++) {
                short8 pf8 = *(const short8*)(Ps + (mf * 16 + r) * 40 + quad * 8);
                acc[mf][0] = MFMA16(pf8, vf0, acc[mf][0]);
                acc[mf][1] = MFMA16(pf8, vf1, acc[mf][1]);
            }
        }
        if (pf) {                       // commit prefetch into the other buffer
            unsigned short* Kn = c ? Kst0 : Kst1;
            unsigned short* Vn = c ? Vst0 : Vst1;
            *(short8*)(Kn + stg_j * 136 + stg_dc * 16) = pk0;
            *(short8*)(Kn + stg_j * 136 + stg_dc * 16 + 8) = pk1;
            *(short8*)(Vn + vd * 40 + vhf * 16) = pv0;
            *(short8*)(Vn + vd * 40 + vhf * 16 + 8) = pv1;
        }
        __syncthreads();
        c ^= 1;
    }

    // epilogue: partial o_slc (gated); single-chunk tiles store, else atomic
    bool single = (qmax < CHUNK);
#pragma unroll
    for (int mf = 0; mf < 4; mf++) {
#pragma unroll
        for (int i = 0; i < 4; i++) {
            int mrow = mf * 16 + quad * 4 + i;
            int gm = mtile * 64 + mrow;
            float gs = g[(size_t)((b * NMAX + gm) * H + h) * 2 + 1];
            float* dst = o_slc_j + (size_t)(o0 + gm) * HD + h * D;
            float v0 = acc[mf][0][i] * gs;
            float v1 = acc[mf][1][i] * gs;
            if (single) {
                dst[(2 * w + 0) * 16 + r] = v0;
                dst[(2 * w + 1) * 16 + r] = v1;
            } else {
                atomicAdd(dst + (2 * w + 0) * 16 + r, v0);
                atomicAdd(dst + (2 * w + 1) * 16 + r, v1);
            }
        }
    }
}

// ---------------------------------------------------------------------------
// K4: padded qp, kp (outputs 1,2) — runs AFTER attention (kp region may have
// been used as scratch for kb16/vt_blk when ws is small)
// ---------------------------------------------------------------------------
__global__ __launch_bounds__(256) void pad_qk_kernel(
    const float* __restrict__ q, const float* __restrict__ k,
    const int* __restrict__ offs,
    float* __restrict__ qp, float* __restrict__ kp) {
    int idx = blockIdx.x * 256 + threadIdx.x;       // float4 index over [B,n,H,D/4]
    int d4 = idx & 31;
    int h  = (idx >> 5) & 7;
    int m  = (idx >> 8) & (NMAX - 1);
    int b  = idx >> 18;
    int o0 = offs[b];
    int len = offs[b + 1] - o0;
    float4 qv = make_float4(0.f, 0.f, 0.f, 0.f);
    float4 kv = qv;
    if (m < len) {
        size_t src = (size_t)(o0 + m) * HD + h * D + d4 * 4;
        qv = *(const float4*)(q + src);
        kv = *(const float4*)(k + src);
    }
    *(float4*)(qp + (size_t)idx * 4) = qv;
    *(float4*)(kp + (size_t)idx * 4) = kv;
}

// ---------------------------------------------------------------------------
// K5: LayerNorm(1024) per stream, gate by u, sum -> out (oc may alias out)
// ---------------------------------------------------------------------------
__global__ __launch_bounds__(256) void ln_combine_kernel(
    const float* __restrict__ oc, const float* __restrict__ os,
    const float* __restrict__ u, float* __restrict__ out) {
    int t = blockIdx.x, tid = threadIdx.x;
    size_t base = (size_t)t * HD;
    float4 xc = *(const float4*)(oc + base + tid * 4);
    float4 xs = *(const float4*)(os + base + tid * 4);
    float4 uu = *(const float4*)(u + base + tid * 4);
    float s_c = xc.x + xc.y + xc.z + xc.w;
    float q_c = xc.x * xc.x + xc.y * xc.y + xc.z * xc.z + xc.w * xc.w;
    float s_s = xs.x + xs.y + xs.z + xs.w;
    float q_s = xs.x * xs.x + xs.y * xs.y + xs.z * xs.z + xs.w * xs.w;
#pragma unroll
    for (int off = 32; off > 0; off >>= 1) {
        s_c += __shfl_xor(s_c, off); q_c += __shfl_xor(q_c, off);
        s_s += __shfl_xor(s_s, off); q_s += __shfl_xor(q_s, off);
    }
    __shared__ float red[4][4];
    int w = tid >> 6, lane = tid & 63;
    if (lane == 0) {
        red[w][0] = s_c; red[w][1] = q_c; red[w][2] = s_s; red[w][3] = q_s;
    }
    __syncthreads();
    float tsc = red[0][0] + red[1][0] + red[2][0] + red[3][0];
    float tqc = red[0][1] + red[1][1] + red[2][1] + red[3][1];
    float tss = red[0][2] + red[1][2] + red[2][2] + red[3][2];
    float tqs = red[0][3] + red[1][3] + red[2][3] + red[3][3];
    const float inv = 1.f / 1024.f;
    float mc = tsc * inv, vc = tqc * inv - mc * mc;
    float ms = tss * inv, vs = tqs * inv - ms * ms;
    float rc = rsqrtf(vc + 1e-5f), rs = rsqrtf(vs + 1e-5f);
    float4 o;
    o.x = ((xc.x - mc) * rc + (xs.x - ms) * rs) * uu.x;
    o.y = ((xc.y - mc) * rc + (xs.y - ms) * rs) * uu.y;
    o.z = ((xc.z - mc) * rc + (xs.z - ms) * rs) * uu.z;
    o.w = ((xc.w - mc) * rc + (xs.w - ms) * rs) * uu.w;
    *(float4*)(out + base + tid * 4) = o;
}

// ---------------------------------------------------------------------------
extern "C" void kernel_launch(void* const* d_in, const int* in_sizes, int n_in,
                              void* d_out, int out_size, void* d_ws, size_t ws_size,
                              hipStream_t stream) {
    const float* q  = (const float*)d_in[0];
    const float* k  = (const float*)d_in[1];
    const float* v  = (const float*)d_in[2];
    const float* u  = (const float*)d_in[3];
    const float* Wg = (const float*)d_in[4];
    const float* bg = (const float*)d_in[5];
    const int* offs = (const int*)d_in[6];   // int32 (jnp default, x64 off)

    int B = in_sizes[6] - 1;
    int T = in_sizes[0] / HD;

    float* out = (float*)d_out;
    float* qp  = out + (size_t)T * HD;
    float* kp  = qp + (size_t)B * NMAX * HD;

    float* o_cmp_j = out;   // aliases final out (safe: see ln_combine)

    char* w = (char*)d_ws;
    float* k_cmp = (float*)w;            w += (size_t)B * NB * HD * 4;
    float* v_cmp = (float*)w;            w += (size_t)B * NB * HD * 4;
    float* g     = (float*)w;            w += (size_t)B * NMAX * H * 2 * 4;
    unsigned* ms_g = (unsigned*)w;       w += (size_t)B * H * NMAX * 4;
    float* o_slc_j = (float*)w;          w += (size_t)T * HD * 4;

    // bf16 scratch: prefer ws tail; else use kp output region (rewritten after)
    size_t kb16_bytes = (size_t)T * HD * 2;
    size_t vt_bytes   = (size_t)B * H * NB * 128 * 32 * 2;
    size_t used = (size_t)(w - (char*)d_ws);
    char* scr = (used + kb16_bytes + vt_bytes <= ws_size) ? w : (char*)kp;
    unsigned short* kb16  = (unsigned short*)scr;
    unsigned short* vt_blk = (unsigned short*)(scr + kb16_bytes);

    int prepBlocks = B * H * NB;
    int cmpBlocks  = (B * NB * HD / 4) / 256;
    int cmpAttnBlocks = B * H * NB;
    int slcBlocks  = B * H * 16 * MC;
    int padBlocks  = (B * NMAX * HD / 4) / 256;

    (void)hipMemsetAsync(o_slc_j, 0, (size_t)T * HD * sizeof(float), stream);
    prep_kernel<<<prepBlocks, 256, 0, stream>>>(q, k, v, Wg, bg, offs, kb16, vt_blk, g);
    compress_kernel<<<cmpBlocks, 256, 0, stream>>>(k, v, offs, k_cmp, v_cmp);
    cmp_attn<<<cmpAttnBlocks, 256, 0, stream>>>(q, k_cmp, v_cmp, g, offs, ms_g, o_cmp_j);
    slc_attn<<<slcBlocks, 256, 0, stream>>>(q, kb16, vt_blk, g, offs, ms_g, o_slc_j);
    pad_qk_kernel<<<padBlocks, 256, 0, stream>>>(q, k, offs, qp, kp);
    ln_combine_kernel<<<T, 256, 0, stream>>>(o_cmp_j, o_slc_j, u, out);
}